// Round 9
// baseline (381.469 us; speedup 1.0000x reference)
//
#include <hip/hip_runtime.h>
#include <stdint.h>

#define B_DIM 4
#define T_DIM 2048
#define C_DIM 2048
#define NH 16
#define HD 128

typedef unsigned short u16;
typedef __attribute__((ext_vector_type(8))) short short8;
typedef __attribute__((ext_vector_type(8))) u16 ushort8;
typedef __attribute__((ext_vector_type(4))) u16 u16x4;
typedef __attribute__((ext_vector_type(2))) uint32_t u32x2;
typedef __attribute__((ext_vector_type(4))) float f32x4;

// scale / sqrt(128) * log2(e), folded into Q-projection epilogue
#define QSCALE (0.08838834764831845f * 1.4426950408889634f)

__device__ __forceinline__ u16 f2bf(float f) {
  uint32_t u = __builtin_bit_cast(uint32_t, f);
  u = (u + 0x7FFFu + ((u >> 16) & 1u)) >> 16;
  return (u16)u;
}

__device__ __forceinline__ uint32_t cvtpk(float lo, float hi) {
  uint32_t r;
  asm("v_cvt_pk_bf16_f32 %0, %1, %2" : "=v"(r) : "v"(lo), "v"(hi));
  return r;
}

__device__ __forceinline__ void gload16(const void* g, void* l) {
  __builtin_amdgcn_global_load_lds(
      (const __attribute__((address_space(1))) void*)g,
      (__attribute__((address_space(3))) void*)l, 16, 0, 0);
}

__device__ __forceinline__ void wait_vm2() { asm volatile("s_waitcnt vmcnt(2)" ::: "memory"); }
__device__ __forceinline__ void wait_vm4() { asm volatile("s_waitcnt vmcnt(4)" ::: "memory"); }
__device__ __forceinline__ void wait_vm0() { asm volatile("s_waitcnt vmcnt(0)" ::: "memory"); }
__device__ __forceinline__ void wait_lg0() {
  asm volatile("s_waitcnt lgkmcnt(0)" ::: "memory");
  __builtin_amdgcn_sched_barrier(0);
}

// ---------------- cast f32 -> bf16, 8 elems/thread ----------------
__global__ void cast_bf16_kernel(const float* __restrict__ src, u16* __restrict__ dst, int n) {
  int i = (blockIdx.x * 256 + threadIdx.x) * 8;
  if (i >= n) return;
  f32x4 a = *(const f32x4*)(src + i);
  f32x4 b = *(const f32x4*)(src + i + 4);
  ushort8 o;
  o[0] = f2bf(a[0]); o[1] = f2bf(a[1]); o[2] = f2bf(a[2]); o[3] = f2bf(a[3]);
  o[4] = f2bf(b[0]); o[5] = f2bf(b[1]); o[6] = f2bf(b[2]); o[7] = f2bf(b[3]);
  *(ushort8*)(dst + i) = o;
}

// fused 4-weight cast
__global__ void cast_w4_kernel(const float* __restrict__ s0, const float* __restrict__ s1,
                               const float* __restrict__ s2, const float* __restrict__ s3,
                               u16* __restrict__ d0, u16* __restrict__ d1,
                               u16* __restrict__ d2, u16* __restrict__ d3) {
  const int a = blockIdx.x >> 11;
  const float* s = a == 0 ? s0 : a == 1 ? s1 : a == 2 ? s2 : s3;
  u16* d = a == 0 ? d0 : a == 1 ? d1 : a == 2 ? d2 : d3;
  int i = ((blockIdx.x & 2047) * 256 + threadIdx.x) * 8;
  f32x4 x = *(const f32x4*)(s + i);
  f32x4 y = *(const f32x4*)(s + i + 4);
  ushort8 o;
  o[0] = f2bf(x[0]); o[1] = f2bf(x[1]); o[2] = f2bf(x[2]); o[3] = f2bf(x[3]);
  o[4] = f2bf(y[0]); o[5] = f2bf(y[1]); o[6] = f2bf(y[2]); o[7] = f2bf(y[3]);
  *(ushort8*)(d + i) = o;
}

// ============ shared 256x256 GEMM core (BK=64, 8 waves, 4 phases) ==========
// Stage schedule: P1 issues all 4 B(t+1) loads, P2 issues all 4 A(t+1) loads.
// Steady-state outstanding entering P1: [B0,B64,B128,B192,A0,A128,A64,A192].
// P1 vmcnt(2) drains B(t)x4 + A(t){0,128}; P2 vmcnt(4) drains A(t){64,192}.
// Every load has 3-4 phases of slack before first consumption.
#define GEMM_CORE(Aptr, Bptr, KDIM)                                            \
  const int tid = threadIdx.x, wid = tid >> 6, lane = tid & 63;                \
  const int wm = wid >> 2, wn = wid & 3;                                       \
  const int srow = (wid << 3) + (lane >> 3);                                   \
  const int scol = ((lane & 7) ^ (lane >> 3)) << 3;                            \
  const u16* Ag = Aptr + (size_t)(bm + srow) * KDIM + scol;                    \
  const u16* Bg = Bptr + (size_t)(bn + srow) * KDIM + scol;                    \
  const int sbase = wid << 9;                                                  \
  const int l15 = lane & 15;                                                   \
  const int o0 = ((lane >> 4) ^ (lane & 7)) << 3;                              \
  const int o1 = ((4 | (lane >> 4)) ^ (lane & 7)) << 3;                        \
  const int ar = ((wm << 7) + l15) << 6;                                       \
  const int br = ((wn << 6) + l15) << 6;                                       \
  f32x4 acc[8][4];                                                             \
  f32x4 zero4 = {0.f, 0.f, 0.f, 0.f};                                          \
  _Pragma("unroll") for (int i = 0; i < 8; ++i)                                \
    _Pragma("unroll") for (int n = 0; n < 4; ++n) acc[i][n] = zero4;           \
  auto stA = [&](int slot, int tc, int r0, int r1) {                           \
    gload16(Ag + (size_t)r0 * KDIM + tc, &lds[slot][(r0 << 6) + sbase]);       \
    gload16(Ag + (size_t)r1 * KDIM + tc, &lds[slot][(r1 << 6) + sbase]);       \
  };                                                                           \
  auto stB = [&](int slot, int tc, int r0, int r1) {                           \
    gload16(Bg + (size_t)r0 * KDIM + tc, &lds[slot][(r0 << 6) + sbase]);       \
    gload16(Bg + (size_t)r1 * KDIM + tc, &lds[slot][(r1 << 6) + sbase]);       \
  };                                                                           \
  stB(2, 0, 0, 64); stB(2, 0, 128, 192);                                       \
  stA(0, 0, 0, 128); stA(0, 0, 64, 192);                                       \
  short8 af[4], bf[4];                                                         \
  const int NT = KDIM >> 6;                                                    \
  _Pragma("unroll 2") for (int t = 0; t < NT; ++t) {                           \
    const int p = t & 1, q = p ^ 1;                                            \
    const int tc = ((t + 1) & (NT - 1)) << 6;                                  \
    /* P1: kk0, acc rows 0-3; stage B(t+1) */                                  \
    wait_vm2();                                                                \
    __builtin_amdgcn_s_barrier();                                              \
    _Pragma("unroll") for (int i = 0; i < 4; ++i)                              \
      af[i] = *(const short8*)&lds[p][ar + (i << 10) + o0];                    \
    _Pragma("unroll") for (int n = 0; n < 4; ++n)                              \
      bf[n] = *(const short8*)&lds[2 + p][br + (n << 10) + o0];                \
    stB(2 + q, tc, 0, 64); stB(2 + q, tc, 128, 192);                           \
    __builtin_amdgcn_s_barrier();                                              \
    wait_lg0();                                                                \
    __builtin_amdgcn_s_setprio(1);                                             \
    _Pragma("unroll") for (int i = 0; i < 4; ++i)                              \
      _Pragma("unroll") for (int n = 0; n < 4; ++n)                            \
        acc[i][n] = __builtin_amdgcn_mfma_f32_16x16x32_bf16(af[i], bf[n], acc[i][n], 0, 0, 0); \
    __builtin_amdgcn_s_setprio(0);                                             \
    /* P2: kk0, acc rows 4-7; stage A(t+1) */                                  \
    wait_vm4();                                                                \
    __builtin_amdgcn_s_barrier();                                              \
    _Pragma("unroll") for (int i = 0; i < 4; ++i)                              \
      af[i] = *(const short8*)&lds[p][ar + 4096 + (i << 10) + o0];             \
    stA(q, tc, 0, 128); stA(q, tc, 64, 192);                                   \
    __builtin_amdgcn_s_barrier();                                              \
    wait_lg0();                                                                \
    __builtin_amdgcn_s_setprio(1);                                             \
    _Pragma("unroll") for (int i = 0; i < 4; ++i)                              \
      _Pragma("unroll") for (int n = 0; n < 4; ++n)                            \
        acc[4 + i][n] = __builtin_amdgcn_mfma_f32_16x16x32_bf16(af[i], bf[n], acc[4 + i][n], 0, 0, 0); \
    __builtin_amdgcn_s_setprio(0);                                             \
    /* P3: kk1, acc rows 0-3 */                                                \
    __builtin_amdgcn_s_barrier();                                              \
    _Pragma("unroll") for (int i = 0; i < 4; ++i)                              \
      af[i] = *(const short8*)&lds[p][ar + (i << 10) + o1];                    \
    _Pragma("unroll") for (int n = 0; n < 4; ++n)                              \
      bf[n] = *(const short8*)&lds[2 + p][br + (n << 10) + o1];                \
    __builtin_amdgcn_s_barrier();                                              \
    wait_lg0();                                                                \
    __builtin_amdgcn_s_setprio(1);                                             \
    _Pragma("unroll") for (int i = 0; i < 4; ++i)                              \
      _Pragma("unroll") for (int n = 0; n < 4; ++n)                            \
        acc[i][n] = __builtin_amdgcn_mfma_f32_16x16x32_bf16(af[i], bf[n], acc[i][n], 0, 0, 0); \
    __builtin_amdgcn_s_setprio(0);                                             \
    /* P4: kk1, acc rows 4-7 */                                                \
    __builtin_amdgcn_s_barrier();                                              \
    _Pragma("unroll") for (int i = 0; i < 4; ++i)                              \
      af[i] = *(const short8*)&lds[p][ar + 4096 + (i << 10) + o1];             \
    __builtin_amdgcn_s_barrier();                                              \
    wait_lg0();                                                                \
    __builtin_amdgcn_s_setprio(1);                                             \
    _Pragma("unroll") for (int i = 0; i < 4; ++i)                              \
      _Pragma("unroll") for (int n = 0; n < 4; ++n)                            \
        acc[4 + i][n] = __builtin_amdgcn_mfma_f32_16x16x32_bf16(af[i], bf[n], acc[4 + i][n], 0, 0, 0); \
    __builtin_amdgcn_s_setprio(0);                                             \
  }                                                                            \
  wait_vm0();

// ---------------- fused QKV projection: x @ {Wq,Wk,Wv}^T -------------------
// grid 768 (32 bm x 24 bn), 512 thr. bn-blocks 0-7 -> Q (bf16*QSCALE),
// 8-15 -> K (bf16), 16-23 -> V (bf16 transposed per batch).
__global__ __launch_bounds__(512, 2)
void gemm_qkv(const u16* __restrict__ A,
              const u16* __restrict__ W0, const u16* __restrict__ W1,
              const u16* __restrict__ W2,
              u16* __restrict__ O0, u16* __restrict__ O1, u16* __restrict__ O2) {
  __shared__ __align__(16) u16 lds[4][16384];
  const int cpx = 96;                                  // 768/8
  const int swz = (blockIdx.x & 7) * cpx + (blockIdx.x >> 3);
  const int bm = (swz / 24) << 8;
  const int bnb = swz % 24;
  const int sel = bnb >> 3;
  const int bn = (bnb & 7) << 8;
  const u16* Bw = sel == 0 ? W0 : sel == 1 ? W1 : W2;

  GEMM_CORE(A, Bw, 2048)

  const int orow = (lane >> 4) << 2;
  const int ocol = lane & 15;
  if (sel == 2) {            // V^T out: [b][n][t]
#pragma unroll
    for (int mi = 0; mi < 8; ++mi)
#pragma unroll
      for (int ni = 0; ni < 4; ++ni) {
        f32x4 v = acc[mi][ni];
        const int row0 = (wm << 7) + mi * 16 + orow;
        const int col = bn + (wn << 6) + ni * 16 + ocol;
        size_t base = (size_t)(bm >> 11) * ((size_t)T_DIM * C_DIM) +
                      (size_t)col * T_DIM + (size_t)((bm & 2047) + row0);
        u16x4 o;
        o[0] = f2bf(v[0]); o[1] = f2bf(v[1]); o[2] = f2bf(v[2]); o[3] = f2bf(v[3]);
        *(u16x4*)&O2[base] = o;
      }
  } else {
    const float sc = sel == 0 ? QSCALE : 1.0f;
    u16* C = sel == 0 ? O0 : O1;
#pragma unroll
    for (int mi = 0; mi < 8; ++mi)
#pragma unroll
      for (int ni = 0; ni < 4; ++ni) {
        f32x4 v = acc[mi][ni];
        const int row0 = (wm << 7) + mi * 16 + orow;
        const int col = bn + (wn << 6) + ni * 16 + ocol;
        size_t base = (size_t)(bm + row0) * C_DIM + col;
#pragma unroll
        for (int r = 0; r < 4; ++r) C[base + (size_t)r * C_DIM] = f2bf(v[r] * sc);
      }
  }
}

// ---------------- output GEMM: y @ Wo^T -> f32 -----------------------------
__global__ __launch_bounds__(512, 2)
void gemm_out(const u16* __restrict__ A, const u16* __restrict__ Bw,
              float* __restrict__ Cout) {
  __shared__ __align__(16) u16 lds[4][16384];
  const int cpx = 32;                                  // 256/8
  const int swz = (blockIdx.x & 7) * cpx + (blockIdx.x >> 3);
  const int bm = (swz >> 3) << 8;
  const int bn = (swz & 7) << 8;

  GEMM_CORE(A, Bw, 2048)

  const int orow = (lane >> 4) << 2;
  const int ocol = lane & 15;
#pragma unroll
  for (int mi = 0; mi < 8; ++mi)
#pragma unroll
    for (int ni = 0; ni < 4; ++ni) {
      f32x4 v = acc[mi][ni];
      const int row0 = (wm << 7) + mi * 16 + orow;
      const int col = bn + (wn << 6) + ni * 16 + ocol;
      size_t base = (size_t)(bm + row0) * C_DIM + col;
#pragma unroll
      for (int r = 0; r < 4; ++r) Cout[base + (size_t)r * C_DIM] = v[r];
    }
}

// ---------------- causal flash attention (swapped-operand, 8 waves) --------
__global__ __launch_bounds__(512, 4)
void attn_kernel(const u16* __restrict__ Qg, const u16* __restrict__ Kg,
                 const u16* __restrict__ VtG, u16* __restrict__ Y) {
  __shared__ __align__(16) u16 Klds[64][136];
  __shared__ __align__(16) u16 Vlds[128][72];
  __shared__ __align__(16) u16 Plds[8][16][72];
  const int f = blockIdx.x;
  const int pair = (f >> 3) & 7;
  const int bh = (f & 7) | ((f >> 6) << 3);   // all 8 pairs of a head on 1 XCD
  const int b = bh >> 4, h = bh & 15;
  const size_t qkbase = (size_t)b * T_DIM * C_DIM + (size_t)h * HD;
  const size_t vtbase = (size_t)b * T_DIM * C_DIM + (size_t)h * HD * T_DIM;
  const int tid = threadIdx.x, wid = tid >> 6, lane = tid & 63;
  const int l15 = lane & 15, g = lane >> 4;

  const int kr = tid >> 4, kc = (tid & 15) * 8;
  const int vr = tid >> 3, vc = (tid & 7) * 8;
  const u16* Kgp = Kg + qkbase + (size_t)kr * C_DIM + kc;
  const u16* Vgp = VtG + vtbase + (size_t)vr * T_DIM + vc;

  auto process = [&](int qb) {
    const int rlo = qb + wid * 16;
    short8 qf[4];
    {
      const u16* qp = Qg + qkbase + (size_t)(rlo + l15) * C_DIM + g * 8;
#pragma unroll
      for (int dc = 0; dc < 4; ++dc) qf[dc] = *(const short8*)(qp + dc * 32);
    }
    f32x4 zero4 = {0.f, 0.f, 0.f, 0.f};
    f32x4 ao[8];
#pragma unroll
    for (int i = 0; i < 8; ++i) ao[i] = zero4;
    float m_run = -1e30f;
    float l_lane = 0.f;
    const int nt = (qb >> 6) + 2;

    ushort8 kN[2], vN[2];
    kN[0] = *(const ushort8*)(Kgp);
    kN[1] = *(const ushort8*)(Kgp + 32 * (size_t)C_DIM);
    vN[0] = *(const ushort8*)(Vgp);
    vN[1] = *(const ushort8*)(Vgp + 64 * (size_t)T_DIM);

    for (int t = 0; t < nt; ++t) {
      const int kb = t * 64;
      __syncthreads();   // LDS free
      *(ushort8*)&Klds[kr][kc]      = kN[0];
      *(ushort8*)&Klds[kr + 32][kc] = kN[1];
      *(ushort8*)&Vlds[vr][vc]      = vN[0];
      *(ushort8*)&Vlds[vr + 64][vc] = vN[1];
      __syncthreads();   // LDS ready
      if (t + 1 < nt) {  // async-STAGE next tile under current compute
        const int nkb = kb + 64;
        kN[0] = *(const ushort8*)(Kgp + (size_t)nkb * C_DIM);
        kN[1] = *(const ushort8*)(Kgp + (size_t)(nkb + 32) * C_DIM);
        vN[0] = *(const ushort8*)(Vgp + nkb);
        vN[1] = *(const ushort8*)(Vgp + 64 * (size_t)T_DIM + nkb);
      }

      if (kb <= rlo + 15) {
        // S^T: lane q = rlo+l15, k = kb + jt*16 + g*4 + r (pre-scaled, log2)
        f32x4 st[4];
        __builtin_amdgcn_s_setprio(1);
#pragma unroll
        for (int jt = 0; jt < 4; ++jt) {
          f32x4 a = zero4;
#pragma unroll
          for (int dc = 0; dc < 4; ++dc) {
            short8 kf = *(const short8*)&Klds[jt * 16 + l15][dc * 32 + g * 8];
            a = __builtin_amdgcn_mfma_f32_16x16x32_bf16(kf, qf[dc], a, 0, 0, 0);
          }
          st[jt] = a;
        }
        __builtin_amdgcn_s_setprio(0);

        // causal mask only on diagonal-overlapping tiles (uniform branch)
        if (kb + 63 > rlo) {
          const int qa = rlo + l15;
#pragma unroll
          for (int jt = 0; jt < 4; ++jt) {
            const int k0 = kb + jt * 16 + g * 4;
#pragma unroll
            for (int r = 0; r < 4; ++r)
              if (k0 + r > qa) st[jt][r] = -1e30f;
          }
        }

        // lane-local max; full reduce + rescale only when threshold exceeded
        float mxl = st[0][0];
#pragma unroll
        for (int jt = 0; jt < 4; ++jt)
#pragma unroll
          for (int r = 0; r < 4; ++r) mxl = fmaxf(mxl, st[jt][r]);
        if (__any(mxl > m_run + 8.0f)) {
          float mx = fmaxf(mxl, __shfl_xor(mxl, 16, 64));
          mx = fmaxf(mx, __shfl_xor(mx, 32, 64));
          float mn = fmaxf(m_run, mx);
          float corr = __builtin_amdgcn_exp2f(m_run - mn);
          m_run = mn;
#pragma unroll
          for (int dc = 0; dc < 8; ++dc)
#pragma unroll
            for (int r = 0; r < 4; ++r) ao[dc][r] *= corr;
          l_lane *= corr;
        }

        // P = exp2(S - m), per-lane sum, pack pairs to LDS [q][k]
#pragma unroll
        for (int jt = 0; jt < 4; ++jt) {
          float p0 = __builtin_amdgcn_exp2f(st[jt][0] - m_run);
          float p1 = __builtin_amdgcn_exp2f(st[jt][1] - m_run);
          float p2 = __builtin_amdgcn_exp2f(st[jt][2] - m_run);
          float p3 = __builtin_amdgcn_exp2f(st[jt][3] - m_run);
          l_lane += (p0 + p1) + (p2 + p3);
          u32x2 w;
          w[0] = cvtpk(p0, p1);
          w[1] = cvtpk(p2, p3);
          *(u32x2*)&Plds[wid][l15][jt * 16 + g * 4] = w;
        }

        // O^T += V^T P^T : lane q = l15, d = dc*16 + g*4 + r
        short8 pf[2];
#pragma unroll
        for (int k2 = 0; k2 < 2; ++k2)
          pf[k2] = *(const short8*)&Plds[wid][l15][k2 * 32 + g * 8];
        __builtin_amdgcn_s_setprio(1);
#pragma unroll
        for (int dc = 0; dc < 8; ++dc) {
#pragma unroll
          for (int k2 = 0; k2 < 2; ++k2) {
            short8 vf = *(const short8*)&Vlds[dc * 16 + l15][k2 * 32 + g * 8];
            ao[dc] = __builtin_amdgcn_mfma_f32_16x16x32_bf16(vf, pf[k2], ao[dc], 0, 0, 0);
          }
        }
        __builtin_amdgcn_s_setprio(0);
      }
    }

    // final l reduce + normalize + write Y
    float l = l_lane;
    l += __shfl_xor(l, 16, 64);
    l += __shfl_xor(l, 32, 64);
    const float rcp = 1.0f / l;
    u16* yp = Y + qkbase + (size_t)(rlo + l15) * C_DIM + g * 4;
#pragma unroll
    for (int dc = 0; dc < 8; ++dc) {
      u32x2 w;
      w[0] = cvtpk(ao[dc][0] * rcp, ao[dc][1] * rcp);
      w[1] = cvtpk(ao[dc][2] * rcp, ao[dc][3] * rcp);
      *(u32x2*)&yp[dc * 16] = w;
    }
  };

  process(pair * 128);
  process((15 - pair) * 128);
}

extern "C" void kernel_launch(void* const* d_in, const int* in_sizes, int n_in,
                              void* d_out, int out_size, void* d_ws, size_t ws_size,
                              hipStream_t stream) {
  const float* x  = (const float*)d_in[0];
  const float* Wq = (const float*)d_in[1];
  const float* Wk = (const float*)d_in[2];
  const float* Wv = (const float*)d_in[3];
  const float* Wo = (const float*)d_in[4];
  float* out = (float*)d_out;

  const size_t SZX = (size_t)8192 * 2048;
  const size_t SZW = (size_t)2048 * 2048;
  u16* xb  = (u16*)d_ws;
  u16* Wqb = xb + SZX;
  u16* Wkb = Wqb + SZW;
  u16* Wvb = Wkb + SZW;
  u16* Wob = Wvb + SZW;
  u16* Qb  = Wob + SZW;   // Q (pre-scaled), overwritten in place by attn Y
  u16* Kb  = Qb + SZX;
  u16* Vb  = Kb + SZX;    // V^T in [b][n][t] layout

  cast_bf16_kernel<<<(int)(SZX / 2048), 256, 0, stream>>>(x, xb, (int)SZX);
  cast_w4_kernel<<<8192, 256, 0, stream>>>(Wq, Wk, Wv, Wo, Wqb, Wkb, Wvb, Wob);

  gemm_qkv<<<768, 512, 0, stream>>>(xb, Wqb, Wkb, Wvb, Qb, Kb, Vb);

  attn_kernel<<<512, 512, 0, stream>>>(Qb, Kb, Vb, Qb);

  gemm_out<<<256, 512, 0, stream>>>(Qb, Wob, out);
}

// Round 10
// 373.559 us; speedup vs baseline: 1.0212x; 1.0212x over previous
//
#include <hip/hip_runtime.h>
#include <stdint.h>

#define B_DIM 4
#define T_DIM 2048
#define C_DIM 2048
#define NH 16
#define HD 128

typedef unsigned short u16;
typedef __attribute__((ext_vector_type(8))) short short8;
typedef __attribute__((ext_vector_type(8))) u16 ushort8;
typedef __attribute__((ext_vector_type(4))) u16 u16x4;
typedef __attribute__((ext_vector_type(2))) uint32_t u32x2;
typedef __attribute__((ext_vector_type(4))) float f32x4;

// scale / sqrt(128) * log2(e), folded into Q-projection epilogue
#define QSCALE (0.08838834764831845f * 1.4426950408889634f)

__device__ __forceinline__ u16 f2bf(float f) {
  uint32_t u = __builtin_bit_cast(uint32_t, f);
  u = (u + 0x7FFFu + ((u >> 16) & 1u)) >> 16;
  return (u16)u;
}

__device__ __forceinline__ uint32_t cvtpk(float lo, float hi) {
  uint32_t r;
  asm("v_cvt_pk_bf16_f32 %0, %1, %2" : "=v"(r) : "v"(lo), "v"(hi));
  return r;
}

__device__ __forceinline__ void gload16(const void* g, void* l) {
  __builtin_amdgcn_global_load_lds(
      (const __attribute__((address_space(1))) void*)g,
      (__attribute__((address_space(3))) void*)l, 16, 0, 0);
}

__device__ __forceinline__ void wait_vm2() { asm volatile("s_waitcnt vmcnt(2)" ::: "memory"); }
__device__ __forceinline__ void wait_vm4() { asm volatile("s_waitcnt vmcnt(4)" ::: "memory"); }
__device__ __forceinline__ void wait_vm0() { asm volatile("s_waitcnt vmcnt(0)" ::: "memory"); }
__device__ __forceinline__ void wait_lg0() {
  asm volatile("s_waitcnt lgkmcnt(0)" ::: "memory");
  __builtin_amdgcn_sched_barrier(0);
}

// ---------------- cast f32 -> bf16, 8 elems/thread ----------------
__global__ void cast_bf16_kernel(const float* __restrict__ src, u16* __restrict__ dst, int n) {
  int i = (blockIdx.x * 256 + threadIdx.x) * 8;
  if (i >= n) return;
  f32x4 a = *(const f32x4*)(src + i);
  f32x4 b = *(const f32x4*)(src + i + 4);
  ushort8 o;
  o[0] = f2bf(a[0]); o[1] = f2bf(a[1]); o[2] = f2bf(a[2]); o[3] = f2bf(a[3]);
  o[4] = f2bf(b[0]); o[5] = f2bf(b[1]); o[6] = f2bf(b[2]); o[7] = f2bf(b[3]);
  *(ushort8*)(dst + i) = o;
}

// fused 4-weight cast
__global__ void cast_w4_kernel(const float* __restrict__ s0, const float* __restrict__ s1,
                               const float* __restrict__ s2, const float* __restrict__ s3,
                               u16* __restrict__ d0, u16* __restrict__ d1,
                               u16* __restrict__ d2, u16* __restrict__ d3) {
  const int a = blockIdx.x >> 11;
  const float* s = a == 0 ? s0 : a == 1 ? s1 : a == 2 ? s2 : s3;
  u16* d = a == 0 ? d0 : a == 1 ? d1 : a == 2 ? d2 : d3;
  int i = ((blockIdx.x & 2047) * 256 + threadIdx.x) * 8;
  f32x4 x = *(const f32x4*)(s + i);
  f32x4 y = *(const f32x4*)(s + i + 4);
  ushort8 o;
  o[0] = f2bf(x[0]); o[1] = f2bf(x[1]); o[2] = f2bf(x[2]); o[3] = f2bf(x[3]);
  o[4] = f2bf(y[0]); o[5] = f2bf(y[1]); o[6] = f2bf(y[2]); o[7] = f2bf(y[3]);
  *(ushort8*)(d + i) = o;
}

// ============ shared 256x256 GEMM core (BK=64, 8 waves, 4 phases) ==========
// Stage schedule: P1 issues all 4 B(t+1) loads, P2 issues all 4 A(t+1) loads.
// Steady-state outstanding entering P1: [B0,B64,B128,B192,A0,A128,A64,A192].
// P1 vmcnt(2) drains B(t)x4 + A(t){0,128}; P2 vmcnt(4) drains A(t){64,192}.
#define GEMM_CORE(Aptr, Bptr, KDIM)                                            \
  const int tid = threadIdx.x, wid = tid >> 6, lane = tid & 63;                \
  const int wm = wid >> 2, wn = wid & 3;                                       \
  const int srow = (wid << 3) + (lane >> 3);                                   \
  const int scol = ((lane & 7) ^ (lane >> 3)) << 3;                            \
  const u16* Ag = Aptr + (size_t)(bm + srow) * KDIM + scol;                    \
  const u16* Bg = Bptr + (size_t)(bn + srow) * KDIM + scol;                    \
  const int sbase = wid << 9;                                                  \
  const int l15 = lane & 15;                                                   \
  const int o0 = ((lane >> 4) ^ (lane & 7)) << 3;                              \
  const int o1 = ((4 | (lane >> 4)) ^ (lane & 7)) << 3;                        \
  const int ar = ((wm << 7) + l15) << 6;                                       \
  const int br = ((wn << 6) + l15) << 6;                                       \
  f32x4 acc[8][4];                                                             \
  f32x4 zero4 = {0.f, 0.f, 0.f, 0.f};                                          \
  _Pragma("unroll") for (int i = 0; i < 8; ++i)                                \
    _Pragma("unroll") for (int n = 0; n < 4; ++n) acc[i][n] = zero4;           \
  auto stA = [&](int slot, int tc, int r0, int r1) {                           \
    gload16(Ag + (size_t)r0 * KDIM + tc, &lds[slot][(r0 << 6) + sbase]);       \
    gload16(Ag + (size_t)r1 * KDIM + tc, &lds[slot][(r1 << 6) + sbase]);       \
  };                                                                           \
  auto stB = [&](int slot, int tc, int r0, int r1) {                           \
    gload16(Bg + (size_t)r0 * KDIM + tc, &lds[slot][(r0 << 6) + sbase]);       \
    gload16(Bg + (size_t)r1 * KDIM + tc, &lds[slot][(r1 << 6) + sbase]);       \
  };                                                                           \
  stB(2, 0, 0, 64); stB(2, 0, 128, 192);                                       \
  stA(0, 0, 0, 128); stA(0, 0, 64, 192);                                       \
  short8 af[4], bf[4];                                                         \
  const int NT = KDIM >> 6;                                                    \
  _Pragma("unroll 2") for (int t = 0; t < NT; ++t) {                           \
    const int p = t & 1, q = p ^ 1;                                            \
    const int tc = ((t + 1) & (NT - 1)) << 6;                                  \
    /* P1: kk0, acc rows 0-3; stage B(t+1) */                                  \
    wait_vm2();                                                                \
    __builtin_amdgcn_s_barrier();                                              \
    _Pragma("unroll") for (int i = 0; i < 4; ++i)                              \
      af[i] = *(const short8*)&lds[p][ar + (i << 10) + o0];                    \
    _Pragma("unroll") for (int n = 0; n < 4; ++n)                              \
      bf[n] = *(const short8*)&lds[2 + p][br + (n << 10) + o0];                \
    stB(2 + q, tc, 0, 64); stB(2 + q, tc, 128, 192);                           \
    __builtin_amdgcn_s_barrier();                                              \
    wait_lg0();                                                                \
    __builtin_amdgcn_s_setprio(1);                                             \
    _Pragma("unroll") for (int i = 0; i < 4; ++i)                              \
      _Pragma("unroll") for (int n = 0; n < 4; ++n)                            \
        acc[i][n] = __builtin_amdgcn_mfma_f32_16x16x32_bf16(af[i], bf[n], acc[i][n], 0, 0, 0); \
    __builtin_amdgcn_s_setprio(0);                                             \
    /* P2: kk0, acc rows 4-7; stage A(t+1) */                                  \
    wait_vm4();                                                                \
    __builtin_amdgcn_s_barrier();                                              \
    _Pragma("unroll") for (int i = 0; i < 4; ++i)                              \
      af[i] = *(const short8*)&lds[p][ar + 4096 + (i << 10) + o0];             \
    stA(q, tc, 0, 128); stA(q, tc, 64, 192);                                   \
    __builtin_amdgcn_s_barrier();                                              \
    wait_lg0();                                                                \
    __builtin_amdgcn_s_setprio(1);                                             \
    _Pragma("unroll") for (int i = 0; i < 4; ++i)                              \
      _Pragma("unroll") for (int n = 0; n < 4; ++n)                            \
        acc[4 + i][n] = __builtin_amdgcn_mfma_f32_16x16x32_bf16(af[i], bf[n], acc[4 + i][n], 0, 0, 0); \
    __builtin_amdgcn_s_setprio(0);                                             \
    /* P3: kk1, acc rows 0-3 */                                                \
    __builtin_amdgcn_s_barrier();                                              \
    _Pragma("unroll") for (int i = 0; i < 4; ++i)                              \
      af[i] = *(const short8*)&lds[p][ar + (i << 10) + o1];                    \
    _Pragma("unroll") for (int n = 0; n < 4; ++n)                              \
      bf[n] = *(const short8*)&lds[2 + p][br + (n << 10) + o1];                \
    __builtin_amdgcn_s_barrier();                                              \
    wait_lg0();                                                                \
    __builtin_amdgcn_s_setprio(1);                                             \
    _Pragma("unroll") for (int i = 0; i < 4; ++i)                              \
      _Pragma("unroll") for (int n = 0; n < 4; ++n)                            \
        acc[i][n] = __builtin_amdgcn_mfma_f32_16x16x32_bf16(af[i], bf[n], acc[i][n], 0, 0, 0); \
    __builtin_amdgcn_s_setprio(0);                                             \
    /* P4: kk1, acc rows 4-7 */                                                \
    __builtin_amdgcn_s_barrier();                                              \
    _Pragma("unroll") for (int i = 0; i < 4; ++i)                              \
      af[i] = *(const short8*)&lds[p][ar + 4096 + (i << 10) + o1];             \
    __builtin_amdgcn_s_barrier();                                              \
    wait_lg0();                                                                \
    __builtin_amdgcn_s_setprio(1);                                             \
    _Pragma("unroll") for (int i = 0; i < 4; ++i)                              \
      _Pragma("unroll") for (int n = 0; n < 4; ++n)                            \
        acc[4 + i][n] = __builtin_amdgcn_mfma_f32_16x16x32_bf16(af[i], bf[n], acc[4 + i][n], 0, 0, 0); \
    __builtin_amdgcn_s_setprio(0);                                             \
  }                                                                            \
  wait_vm0();

// ---------------- fused QKV projection: x @ {Wq,Wk,Wv}^T -------------------
// grid 768, GROUPED by output: blocks [0,256)->Q, [256,512)->K, [512,768)->V.
// Each 256-group uses the standalone-launch XCD swizzle (4 A-panels x 8
// B-panels = 12MB working set per XCD chunk), restoring round-8 L2 behavior.
__global__ __launch_bounds__(512, 2)
void gemm_qkv(const u16* __restrict__ A,
              const u16* __restrict__ W0, const u16* __restrict__ W1,
              const u16* __restrict__ W2,
              u16* __restrict__ O0, u16* __restrict__ O1, u16* __restrict__ O2) {
  __shared__ __align__(16) u16 lds[4][16384];
  const int sel = blockIdx.x >> 8;
  const int inner = blockIdx.x & 255;
  const int swz = (inner & 7) * 32 + (inner >> 3);
  const int bm = (swz >> 3) << 8;
  const int bn = (swz & 7) << 8;
  const u16* Bw = sel == 0 ? W0 : sel == 1 ? W1 : W2;

  GEMM_CORE(A, Bw, 2048)

  const int orow = (lane >> 4) << 2;
  const int ocol = lane & 15;
  if (sel == 2) {            // V^T out: [b][n][t]
#pragma unroll
    for (int mi = 0; mi < 8; ++mi)
#pragma unroll
      for (int ni = 0; ni < 4; ++ni) {
        f32x4 v = acc[mi][ni];
        const int row0 = (wm << 7) + mi * 16 + orow;
        const int col = bn + (wn << 6) + ni * 16 + ocol;
        size_t base = (size_t)(bm >> 11) * ((size_t)T_DIM * C_DIM) +
                      (size_t)col * T_DIM + (size_t)((bm & 2047) + row0);
        u16x4 o;
        o[0] = f2bf(v[0]); o[1] = f2bf(v[1]); o[2] = f2bf(v[2]); o[3] = f2bf(v[3]);
        *(u16x4*)&O2[base] = o;
      }
  } else {
    const float sc = sel == 0 ? QSCALE : 1.0f;
    u16* C = sel == 0 ? O0 : O1;
#pragma unroll
    for (int mi = 0; mi < 8; ++mi)
#pragma unroll
      for (int ni = 0; ni < 4; ++ni) {
        f32x4 v = acc[mi][ni];
        const int row0 = (wm << 7) + mi * 16 + orow;
        const int col = bn + (wn << 6) + ni * 16 + ocol;
        size_t base = (size_t)(bm + row0) * C_DIM + col;
#pragma unroll
        for (int r = 0; r < 4; ++r) C[base + (size_t)r * C_DIM] = f2bf(v[r] * sc);
      }
  }
}

// ---------------- output GEMM: y @ Wo^T -> f32 -----------------------------
__global__ __launch_bounds__(512, 2)
void gemm_out(const u16* __restrict__ A, const u16* __restrict__ Bw,
              float* __restrict__ Cout) {
  __shared__ __align__(16) u16 lds[4][16384];
  const int swz = (blockIdx.x & 7) * 32 + (blockIdx.x >> 3);
  const int bm = (swz >> 3) << 8;
  const int bn = (swz & 7) << 8;

  GEMM_CORE(A, Bw, 2048)

  const int orow = (lane >> 4) << 2;
  const int ocol = lane & 15;
#pragma unroll
  for (int mi = 0; mi < 8; ++mi)
#pragma unroll
    for (int ni = 0; ni < 4; ++ni) {
      f32x4 v = acc[mi][ni];
      const int row0 = (wm << 7) + mi * 16 + orow;
      const int col = bn + (wn << 6) + ni * 16 + ocol;
      size_t base = (size_t)(bm + row0) * C_DIM + col;
#pragma unroll
      for (int r = 0; r < 4; ++r) Cout[base + (size_t)r * C_DIM] = v[r];
    }
}

// ---------------- causal flash attention (swapped-operand, 8 waves) --------
__global__ __launch_bounds__(512, 4)
void attn_kernel(const u16* __restrict__ Qg, const u16* __restrict__ Kg,
                 const u16* __restrict__ VtG, u16* __restrict__ Y) {
  __shared__ __align__(16) u16 Klds[64][136];
  __shared__ __align__(16) u16 Vlds[128][72];
  __shared__ __align__(16) u16 Plds[8][16][72];
  const int f = blockIdx.x;
  const int pair = (f >> 3) & 7;
  const int bh = (f & 7) | ((f >> 6) << 3);   // all 8 pairs of a head on 1 XCD
  const int b = bh >> 4, h = bh & 15;
  const size_t qkbase = (size_t)b * T_DIM * C_DIM + (size_t)h * HD;
  const size_t vtbase = (size_t)b * T_DIM * C_DIM + (size_t)h * HD * T_DIM;
  const int tid = threadIdx.x, wid = tid >> 6, lane = tid & 63;
  const int l15 = lane & 15, g = lane >> 4;

  const int kr = tid >> 4, kc = (tid & 15) * 8;
  const int vr = tid >> 3, vc = (tid & 7) * 8;
  const u16* Kgp = Kg + qkbase + (size_t)kr * C_DIM + kc;
  const u16* Vgp = VtG + vtbase + (size_t)vr * T_DIM + vc;

  auto process = [&](int qb) {
    const int rlo = qb + wid * 16;
    short8 qf[4];
    {
      const u16* qp = Qg + qkbase + (size_t)(rlo + l15) * C_DIM + g * 8;
#pragma unroll
      for (int dc = 0; dc < 4; ++dc) qf[dc] = *(const short8*)(qp + dc * 32);
    }
    f32x4 zero4 = {0.f, 0.f, 0.f, 0.f};
    f32x4 ao[8];
#pragma unroll
    for (int i = 0; i < 8; ++i) ao[i] = zero4;
    float m_run = -1e30f;
    float l_lane = 0.f;
    const int nt = (qb >> 6) + 2;

    ushort8 kN[2], vN[2];
    kN[0] = *(const ushort8*)(Kgp);
    kN[1] = *(const ushort8*)(Kgp + 32 * (size_t)C_DIM);
    vN[0] = *(const ushort8*)(Vgp);
    vN[1] = *(const ushort8*)(Vgp + 64 * (size_t)T_DIM);

    for (int t = 0; t < nt; ++t) {
      const int kb = t * 64;
      __syncthreads();   // LDS free
      *(ushort8*)&Klds[kr][kc]      = kN[0];
      *(ushort8*)&Klds[kr + 32][kc] = kN[1];
      *(ushort8*)&Vlds[vr][vc]      = vN[0];
      *(ushort8*)&Vlds[vr + 64][vc] = vN[1];
      __syncthreads();   // LDS ready
      if (t + 1 < nt) {  // async-STAGE next tile under current compute
        const int nkb = kb + 64;
        kN[0] = *(const ushort8*)(Kgp + (size_t)nkb * C_DIM);
        kN[1] = *(const ushort8*)(Kgp + (size_t)(nkb + 32) * C_DIM);
        vN[0] = *(const ushort8*)(Vgp + nkb);
        vN[1] = *(const ushort8*)(Vgp + 64 * (size_t)T_DIM + nkb);
      }

      if (kb <= rlo + 15) {
        // S^T: lane q = rlo+l15, k = kb + jt*16 + g*4 + r (pre-scaled, log2)
        f32x4 st[4];
        __builtin_amdgcn_s_setprio(1);
#pragma unroll
        for (int jt = 0; jt < 4; ++jt) {
          f32x4 a = zero4;
#pragma unroll
          for (int dc = 0; dc < 4; ++dc) {
            short8 kf = *(const short8*)&Klds[jt * 16 + l15][dc * 32 + g * 8];
            a = __builtin_amdgcn_mfma_f32_16x16x32_bf16(kf, qf[dc], a, 0, 0, 0);
          }
          st[jt] = a;
        }
        __builtin_amdgcn_s_setprio(0);

        // causal mask only on diagonal-overlapping tiles (uniform branch)
        if (kb + 63 > rlo) {
          const int qa = rlo + l15;
#pragma unroll
          for (int jt = 0; jt < 4; ++jt) {
            const int k0 = kb + jt * 16 + g * 4;
#pragma unroll
            for (int r = 0; r < 4; ++r)
              if (k0 + r > qa) st[jt][r] = -1e30f;
          }
        }

        // lane-local max; full reduce + rescale only when threshold exceeded
        float mxl = st[0][0];
#pragma unroll
        for (int jt = 0; jt < 4; ++jt)
#pragma unroll
          for (int r = 0; r < 4; ++r) mxl = fmaxf(mxl, st[jt][r]);
        if (__any(mxl > m_run + 8.0f)) {
          float mx = fmaxf(mxl, __shfl_xor(mxl, 16, 64));
          mx = fmaxf(mx, __shfl_xor(mx, 32, 64));
          float mn = fmaxf(m_run, mx);
          float corr = __builtin_amdgcn_exp2f(m_run - mn);
          m_run = mn;
#pragma unroll
          for (int dc = 0; dc < 8; ++dc)
#pragma unroll
            for (int r = 0; r < 4; ++r) ao[dc][r] *= corr;
          l_lane *= corr;
        }

        // P = exp2(S - m), per-lane sum, pack pairs to LDS [q][k]
#pragma unroll
        for (int jt = 0; jt < 4; ++jt) {
          float p0 = __builtin_amdgcn_exp2f(st[jt][0] - m_run);
          float p1 = __builtin_amdgcn_exp2f(st[jt][1] - m_run);
          float p2 = __builtin_amdgcn_exp2f(st[jt][2] - m_run);
          float p3 = __builtin_amdgcn_exp2f(st[jt][3] - m_run);
          l_lane += (p0 + p1) + (p2 + p3);
          u32x2 w;
          w[0] = cvtpk(p0, p1);
          w[1] = cvtpk(p2, p3);
          *(u32x2*)&Plds[wid][l15][jt * 16 + g * 4] = w;
        }

        // O^T += V^T P^T : lane q = l15, d = dc*16 + g*4 + r
        short8 pf[2];
#pragma unroll
        for (int k2 = 0; k2 < 2; ++k2)
          pf[k2] = *(const short8*)&Plds[wid][l15][k2 * 32 + g * 8];
        __builtin_amdgcn_s_setprio(1);
#pragma unroll
        for (int dc = 0; dc < 8; ++dc) {
#pragma unroll
          for (int k2 = 0; k2 < 2; ++k2) {
            short8 vf = *(const short8*)&Vlds[dc * 16 + l15][k2 * 32 + g * 8];
            ao[dc] = __builtin_amdgcn_mfma_f32_16x16x32_bf16(vf, pf[k2], ao[dc], 0, 0, 0);
          }
        }
        __builtin_amdgcn_s_setprio(0);
      }
    }

    // final l reduce + normalize + write Y
    float l = l_lane;
    l += __shfl_xor(l, 16, 64);
    l += __shfl_xor(l, 32, 64);
    const float rcp = 1.0f / l;
    u16* yp = Y + qkbase + (size_t)(rlo + l15) * C_DIM + g * 4;
#pragma unroll
    for (int dc = 0; dc < 8; ++dc) {
      u32x2 w;
      w[0] = cvtpk(ao[dc][0] * rcp, ao[dc][1] * rcp);
      w[1] = cvtpk(ao[dc][2] * rcp, ao[dc][3] * rcp);
      *(u32x2*)&yp[dc * 16] = w;
    }
  };

  process(pair * 128);
  process((15 - pair) * 128);
}

extern "C" void kernel_launch(void* const* d_in, const int* in_sizes, int n_in,
                              void* d_out, int out_size, void* d_ws, size_t ws_size,
                              hipStream_t stream) {
  const float* x  = (const float*)d_in[0];
  const float* Wq = (const float*)d_in[1];
  const float* Wk = (const float*)d_in[2];
  const float* Wv = (const float*)d_in[3];
  const float* Wo = (const float*)d_in[4];
  float* out = (float*)d_out;

  const size_t SZX = (size_t)8192 * 2048;
  const size_t SZW = (size_t)2048 * 2048;
  u16* xb  = (u16*)d_ws;
  u16* Wqb = xb + SZX;
  u16* Wkb = Wqb + SZW;
  u16* Wvb = Wkb + SZW;
  u16* Wob = Wvb + SZW;
  u16* Qb  = Wob + SZW;   // Q (pre-scaled), overwritten in place by attn Y
  u16* Kb  = Qb + SZX;
  u16* Vb  = Kb + SZX;    // V^T in [b][n][t] layout

  cast_bf16_kernel<<<(int)(SZX / 2048), 256, 0, stream>>>(x, xb, (int)SZX);
  cast_w4_kernel<<<8192, 256, 0, stream>>>(Wq, Wk, Wv, Wo, Wqb, Wkb, Wvb, Wob);

  gemm_qkv<<<768, 512, 0, stream>>>(xb, Wqb, Wkb, Wvb, Qb, Kb, Vb);

  attn_kernel<<<512, 512, 0, stream>>>(Qb, Kb, Vb, Qb);

  gemm_out<<<256, 512, 0, stream>>>(Qb, Wob, out);
}